// Round 1
// baseline (649.811 us; speedup 1.0000x reference)
//
#include <hip/hip_runtime.h>
#include <math.h>

#define NN 50000
#define EE 800000
#define INC 128
#define HIDC 64
#define OUTC 64
#define LLAYERS 8
#define TOT (EE + NN)

// ---------------------------------------------------------------------------
// Stage 0: detect whether edge_index was delivered as int64 or int32.
// Deterministic: depends only on input contents. If the buffer is truly int64,
// the first EE int64 values (row indices) all lie in [0, NN). If it is int32,
// int64-interpretation pairs adjacent int32s; any nonzero odd-position word
// pushes the value out of range (certain over 800K random indices).
// Reads exactly EE*8 = 6.4 MB, within bounds for both layouts.
__global__ void detect_kernel(const long long* __restrict__ p, int* __restrict__ flag) {
    int stride = gridDim.x * blockDim.x;
    int bad = 0;
    for (int i = blockIdx.x * blockDim.x + threadIdx.x; i < EE; i += stride) {
        long long v = p[i];
        bad |= (v < 0 || v >= NN);
    }
    if (bad) atomicOr(flag, 1);   // flag=1 -> int32 layout
}

__device__ __forceinline__ int load_row(const void* ei, int is64, int e) {
    return is64 ? (int)((const long long*)ei)[e] : ((const int*)ei)[e];
}
__device__ __forceinline__ int load_col(const void* ei, int is64, int e) {
    return is64 ? (int)((const long long*)ei)[EE + e] : ((const int*)ei)[EE + e];
}

// Stage 1: in-degree of col (self-loops included)
__global__ void deg_kernel(const void* __restrict__ ei, const int* __restrict__ flag,
                           int* __restrict__ degi) {
    int i = blockIdx.x * blockDim.x + threadIdx.x;
    if (i >= TOT) return;
    int is64 = (*flag == 0);
    int c = (i < EE) ? load_col(ei, is64, i) : (i - EE);
    atomicAdd(&degi[c], 1);
}

__global__ void dinv_kernel(const int* __restrict__ degi, float* __restrict__ dinv) {
    int i = blockIdx.x * blockDim.x + threadIdx.x;
    if (i < NN) {
        int d = degi[i];
        dinv[i] = d > 0 ? 1.0f / sqrtf((float)d) : 0.0f;
    }
}

// Stage 2: exclusive prefix sum over degrees (single block, N=50000 is tiny)
__global__ __launch_bounds__(1024) void scan_kernel(const int* __restrict__ degi,
                                                    int* __restrict__ offsets) {
    __shared__ int sums[1024];
    int t = threadIdx.x;
    const int chunk = (NN + 1023) / 1024;
    int lo = t * chunk; if (lo > NN) lo = NN;
    int hi = lo + chunk; if (hi > NN) hi = NN;
    int s = 0;
    for (int i = lo; i < hi; ++i) s += degi[i];
    sums[t] = s;
    __syncthreads();
    for (int off = 1; off < 1024; off <<= 1) {
        int add = (t >= off) ? sums[t - off] : 0;
        __syncthreads();
        sums[t] += add;
        __syncthreads();
    }
    int run = sums[t] - s;  // exclusive prefix for this chunk
    for (int i = lo; i < hi; ++i) { offsets[i] = run; run += degi[i]; }
    if (t == 1023) offsets[NN] = sums[1023];
}

// Stage 3: fill CSR adjacency (src, norm) sorted by destination
__global__ void fill_kernel(const void* __restrict__ ei, const int* __restrict__ flag,
                            const float* __restrict__ dinv, int* __restrict__ cursor,
                            int2* __restrict__ adj) {
    int i = blockIdx.x * blockDim.x + threadIdx.x;
    if (i >= TOT) return;
    int is64 = (*flag == 0);
    int r, c;
    if (i < EE) { r = load_row(ei, is64, i); c = load_col(ei, is64, i); }
    else        { r = i - EE; c = r; }
    int pos = atomicAdd(&cursor[c], 1);
    adj[pos] = make_int2(r, __float_as_int(dinv[r] * dinv[c]));
}

// Stage 4: h = relu(x @ w_in^T + b_in); also x0 = h.
// One wave per node, lane = output channel. w_in^T staged in LDS padded to
// stride 65 (conflict-free lane-consecutive reads); x row staged per wave.
__global__ __launch_bounds__(256) void in_gemm(const float* __restrict__ x,
                                               const float* __restrict__ w_in,
                                               const float* __restrict__ b_in,
                                               float* __restrict__ h,
                                               float* __restrict__ x0) {
    __shared__ float wT[INC * 65];
    __shared__ float xs[4][INC];
    int tid = threadIdx.x;
    for (int i = tid; i < HIDC * INC; i += 256) {
        int j = i >> 7, k = i & 127;          // w_in[j][k], row-major [64][128]
        wT[k * 65 + j] = w_in[i];
    }
    __syncthreads();
    int w = tid >> 6, lane = tid & 63;
    float bj = b_in[lane];
    for (int n0 = blockIdx.x * 4; n0 < NN; n0 += gridDim.x * 4) {
        int n = n0 + w;
        bool valid = n < NN;
        if (valid) {
            xs[w][lane]      = x[(size_t)n * INC + lane];
            xs[w][lane + 64] = x[(size_t)n * INC + 64 + lane];
        }
        __syncthreads();
        if (valid) {
            float acc = bj;
            #pragma unroll 8
            for (int k = 0; k < INC; ++k)
                acc = fmaf(xs[w][k], wT[k * 65 + lane], acc);
            float v = fmaxf(acc, 0.0f);
            h[(size_t)n * HIDC + lane]  = v;
            x0[(size_t)n * HIDC + lane] = v;
        }
        __syncthreads();
    }
}

// Stage 5: one fused GCNII layer.
//   agg = 0.9 * segsum(h[src]*norm) + 0.1 * x0
//   out = (1-beta)*agg + beta*(agg @ W^T);  h_new = relu(out)
// FINAL additionally computes h_new @ w_out^T + b_out into d_out.
template <bool FINAL>
__global__ __launch_bounds__(256) void layer_kernel(
        const float* __restrict__ h_in, float* __restrict__ h_out,
        const float* __restrict__ x0,
        const int* __restrict__ offsets, const int2* __restrict__ adj,
        const float* __restrict__ W, float beta,
        const float* __restrict__ w_out, const float* __restrict__ b_out,
        float* __restrict__ out) {
    __shared__ float WT[HIDC * 65];
    __shared__ float WoT[FINAL ? HIDC * 65 : 1];
    __shared__ float vecs[4][HIDC];
    int tid = threadIdx.x;
    for (int i = tid; i < HIDC * HIDC; i += 256) {
        int j = i >> 6, k = i & 63;           // W[j][k], row-major [64][64]
        WT[k * 65 + j] = W[i];
        if constexpr (FINAL) WoT[k * 65 + j] = w_out[i];
    }
    __syncthreads();
    int w = tid >> 6, lane = tid & 63;
    float omb = 1.0f - beta;
    float boj = 0.0f;
    if constexpr (FINAL) boj = b_out[lane];

    for (int n0 = blockIdx.x * 4; n0 < NN; n0 += gridDim.x * 4) {
        int n = n0 + w;
        bool valid = n < NN;                  // uniform per wave
        float agg = 0.0f;
        if (valid) {
            int e  = offsets[n];
            int e1 = offsets[n + 1];
            float acc = 0.0f;
            for (; e + 4 <= e1; e += 4) {     // unroll-4: overlap gather latency
                int2 a0 = adj[e], a1 = adj[e + 1], a2 = adj[e + 2], a3 = adj[e + 3];
                float h0 = h_in[(size_t)a0.x * HIDC + lane];
                float h1 = h_in[(size_t)a1.x * HIDC + lane];
                float h2 = h_in[(size_t)a2.x * HIDC + lane];
                float h3 = h_in[(size_t)a3.x * HIDC + lane];
                acc = fmaf(__int_as_float(a0.y), h0, acc);
                acc = fmaf(__int_as_float(a1.y), h1, acc);
                acc = fmaf(__int_as_float(a2.y), h2, acc);
                acc = fmaf(__int_as_float(a3.y), h3, acc);
            }
            for (; e < e1; ++e) {
                int2 a = adj[e];
                acc = fmaf(__int_as_float(a.y), h_in[(size_t)a.x * HIDC + lane], acc);
            }
            agg = 0.9f * acc + 0.1f * x0[(size_t)n * HIDC + lane];
        }
        vecs[w][lane] = agg;
        __syncthreads();
        float hn = 0.0f;
        if (valid) {
            float dot = 0.0f;
            #pragma unroll 8
            for (int k = 0; k < HIDC; ++k)
                dot = fmaf(vecs[w][k], WT[k * 65 + lane], dot);
            hn = fmaxf(fmaf(beta, dot, omb * agg), 0.0f);
            if constexpr (!FINAL) h_out[(size_t)n * HIDC + lane] = hn;
        }
        __syncthreads();
        if constexpr (FINAL) {
            vecs[w][lane] = hn;
            __syncthreads();
            if (valid) {
                float acc2 = boj;
                #pragma unroll 8
                for (int k = 0; k < HIDC; ++k)
                    acc2 = fmaf(vecs[w][k], WoT[k * 65 + lane], acc2);
                out[(size_t)n * OUTC + lane] = acc2;
            }
            __syncthreads();
        }
    }
}

extern "C" void kernel_launch(void* const* d_in, const int* in_sizes, int n_in,
                              void* d_out, int out_size, void* d_ws, size_t ws_size,
                              hipStream_t stream) {
    const float* x      = (const float*)d_in[0];
    const void*  ei     = d_in[1];
    const float* w_in   = (const float*)d_in[2];
    const float* b_in   = (const float*)d_in[3];
    const float* conv_w = (const float*)d_in[4];
    const float* w_out  = (const float*)d_in[5];
    const float* b_out  = (const float*)d_in[6];
    float* out = (float*)d_out;

    char* ws = (char*)d_ws;
    size_t off = 0;
    auto alloc = [&](size_t bytes) -> void* {
        void* p = ws + off;
        off += (bytes + 255) & ~(size_t)255;
        return p;
    };
    int*   flag    = (int*)alloc(4);
    int*   degi    = (int*)alloc((size_t)NN * 4);
    float* dinv    = (float*)alloc((size_t)NN * 4);
    int*   offsets = (int*)alloc((size_t)(NN + 1) * 4);
    int*   cursor  = (int*)alloc((size_t)NN * 4);
    int2*  adj     = (int2*)alloc((size_t)TOT * 8);
    float* hA      = (float*)alloc((size_t)NN * HIDC * 4);
    float* hB      = (float*)alloc((size_t)NN * HIDC * 4);
    float* x0      = (float*)alloc((size_t)NN * HIDC * 4);

    hipMemsetAsync(flag, 0, 4, stream);
    hipMemsetAsync(degi, 0, (size_t)NN * 4, stream);
    detect_kernel<<<256, 256, 0, stream>>>((const long long*)ei, flag);
    deg_kernel<<<(TOT + 255) / 256, 256, 0, stream>>>(ei, flag, degi);
    dinv_kernel<<<(NN + 255) / 256, 256, 0, stream>>>(degi, dinv);
    scan_kernel<<<1, 1024, 0, stream>>>(degi, offsets);
    hipMemcpyAsync(cursor, offsets, (size_t)NN * 4, hipMemcpyDeviceToDevice, stream);
    fill_kernel<<<(TOT + 255) / 256, 256, 0, stream>>>(ei, flag, dinv, cursor, adj);
    in_gemm<<<1024, 256, 0, stream>>>(x, w_in, b_in, hA, x0);

    float* cur = hA;
    float* nxt = hB;
    for (int l = 0; l < LLAYERS; ++l) {
        float beta = logf(0.5f / (float)(l + 1) + 1.0f);
        const float* Wl = conv_w + (size_t)l * HIDC * HIDC;
        if (l < LLAYERS - 1) {
            layer_kernel<false><<<2048, 256, 0, stream>>>(cur, nxt, x0, offsets, adj,
                                                          Wl, beta, nullptr, nullptr, nullptr);
            float* t = cur; cur = nxt; nxt = t;
        } else {
            layer_kernel<true><<<2048, 256, 0, stream>>>(cur, nxt, x0, offsets, adj,
                                                         Wl, beta, w_out, b_out, out);
        }
    }
}

// Round 5
// 564.392 us; speedup vs baseline: 1.1513x; 1.1513x over previous
//
#include <hip/hip_runtime.h>
#include <math.h>

#define NN 50000
#define EE 800000
#define INC 128
#define HIDC 64
#define OUTC 64
#define LLAYERS 8
#define TOT (EE + NN)

// ---------------------------------------------------------------------------
// Stage 0: detect whether edge_index was delivered as int64 or int32.
__global__ void detect_kernel(const long long* __restrict__ p, int* __restrict__ flag) {
    int stride = gridDim.x * blockDim.x;
    int bad = 0;
    for (int i = blockIdx.x * blockDim.x + threadIdx.x; i < EE; i += stride) {
        long long v = p[i];
        bad |= (v < 0 || v >= NN);
    }
    if (bad) atomicOr(flag, 1);   // flag=1 -> int32 layout
}

__device__ __forceinline__ int load_row(const void* ei, int is64, int e) {
    return is64 ? (int)((const long long*)ei)[e] : ((const int*)ei)[e];
}
__device__ __forceinline__ int load_col(const void* ei, int is64, int e) {
    return is64 ? (int)((const long long*)ei)[EE + e] : ((const int*)ei)[EE + e];
}

// Stage 1: in-degree of col (self-loops included)
__global__ void deg_kernel(const void* __restrict__ ei, const int* __restrict__ flag,
                           int* __restrict__ degi) {
    int i = blockIdx.x * blockDim.x + threadIdx.x;
    if (i >= TOT) return;
    int is64 = (*flag == 0);
    int c = (i < EE) ? load_col(ei, is64, i) : (i - EE);
    atomicAdd(&degi[c], 1);
}

__global__ void dinv_kernel(const int* __restrict__ degi, float* __restrict__ dinv) {
    int i = blockIdx.x * blockDim.x + threadIdx.x;
    if (i < NN) {
        int d = degi[i];
        dinv[i] = d > 0 ? 1.0f / sqrtf((float)d) : 0.0f;
    }
}

// Stage 2: exclusive prefix sum over degrees (single block)
__global__ __launch_bounds__(1024) void scan_kernel(const int* __restrict__ degi,
                                                    int* __restrict__ offsets) {
    __shared__ int sums[1024];
    int t = threadIdx.x;
    const int chunk = (NN + 1023) / 1024;
    int lo = t * chunk; if (lo > NN) lo = NN;
    int hi = lo + chunk; if (hi > NN) hi = NN;
    int s = 0;
    for (int i = lo; i < hi; ++i) s += degi[i];
    sums[t] = s;
    __syncthreads();
    for (int off = 1; off < 1024; off <<= 1) {
        int add = (t >= off) ? sums[t - off] : 0;
        __syncthreads();
        sums[t] += add;
        __syncthreads();
    }
    int run = sums[t] - s;  // exclusive prefix for this chunk
    for (int i = lo; i < hi; ++i) { offsets[i] = run; run += degi[i]; }
    if (t == 1023) offsets[NN] = sums[1023];
}

// Stage 3: fill CSR adjacency (src, norm) sorted by destination
__global__ void fill_kernel(const void* __restrict__ ei, const int* __restrict__ flag,
                            const float* __restrict__ dinv, int* __restrict__ cursor,
                            int2* __restrict__ adj) {
    int i = blockIdx.x * blockDim.x + threadIdx.x;
    if (i >= TOT) return;
    int is64 = (*flag == 0);
    int r, c;
    if (i < EE) { r = load_row(ei, is64, i); c = load_col(ei, is64, i); }
    else        { r = i - EE; c = r; }
    int pos = atomicAdd(&cursor[c], 1);
    adj[pos] = make_int2(r, __float_as_int(dinv[r] * dinv[c]));
}

// Stage 4: h = relu(x @ w_in^T + b_in); also x0 = h.
__global__ __launch_bounds__(256) void in_gemm(const float* __restrict__ x,
                                               const float* __restrict__ w_in,
                                               const float* __restrict__ b_in,
                                               float* __restrict__ h,
                                               float* __restrict__ x0) {
    __shared__ float wT[INC * 65];
    __shared__ float xs[4][INC];
    int tid = threadIdx.x;
    for (int i = tid; i < HIDC * INC; i += 256) {
        int j = i >> 7, k = i & 127;          // w_in[j][k], row-major [64][128]
        wT[k * 65 + j] = w_in[i];
    }
    __syncthreads();
    int w = tid >> 6, lane = tid & 63;
    float bj = b_in[lane];
    for (int n0 = blockIdx.x * 4; n0 < NN; n0 += gridDim.x * 4) {
        int n = n0 + w;
        bool valid = n < NN;
        if (valid) {
            xs[w][lane]      = x[(size_t)n * INC + lane];
            xs[w][lane + 64] = x[(size_t)n * INC + 64 + lane];
        }
        __syncthreads();
        if (valid) {
            float acc = bj;
            #pragma unroll 8
            for (int k = 0; k < INC; ++k)
                acc = fmaf(xs[w][k], wT[k * 65 + lane], acc);
            float v = fmaxf(acc, 0.0f);
            h[(size_t)n * HIDC + lane]  = v;
            x0[(size_t)n * HIDC + lane] = v;
        }
        __syncthreads();
    }
}

// ---------------------------------------------------------------------------
// Gather core: wave handles node n. lane = g*16 + c (g = edge-group 0..3,
// c = channel-quad 0..15). Group g walks edges e0+g, e0+g+4, ... Each
// vector-load instruction fetches FOUR distinct h rows (4 groups x 16 lanes
// x float4 = 4 x 256B), quadrupling cache lines in flight vs lane=channel.
__device__ __forceinline__ float4 gather_node(const float* __restrict__ h_in,
                                              const int2* __restrict__ adj,
                                              int e0, int e1, int g, int c) {
    float4 acc = make_float4(0.f, 0.f, 0.f, 0.f);
    #pragma unroll 2
    for (int e = e0 + g; e < e1; e += 4) {
        int2 a = adj[e];
        const float4 hv = *reinterpret_cast<const float4*>(h_in + ((a.x << 6) + (c << 2)));
        float nrm = __int_as_float(a.y);
        acc.x = fmaf(nrm, hv.x, acc.x);
        acc.y = fmaf(nrm, hv.y, acc.y);
        acc.z = fmaf(nrm, hv.z, acc.z);
        acc.w = fmaf(nrm, hv.w, acc.w);
    }
    // reduce across the 4 groups (lanes differing in bits 4..5)
    acc.x += __shfl_xor(acc.x, 16); acc.y += __shfl_xor(acc.y, 16);
    acc.z += __shfl_xor(acc.z, 16); acc.w += __shfl_xor(acc.w, 16);
    acc.x += __shfl_xor(acc.x, 32); acc.y += __shfl_xor(acc.y, 32);
    acc.z += __shfl_xor(acc.z, 32); acc.w += __shfl_xor(acc.w, 32);
    return acc;
}

// Stage 5a: middle GCNII layer (separate function so LDS stays at ~17.7KB ->
// 8 blocks/CU; the templated ternary previously allocated 34KB in BOTH
// instantiations per rocprof).
__global__ __launch_bounds__(256) void layer_mid(
        const float* __restrict__ h_in, float* __restrict__ h_out,
        const float* __restrict__ x0,
        const int* __restrict__ offsets, const int2* __restrict__ adj,
        const float* __restrict__ W, float beta) {
    __shared__ float WT[HIDC * 65];
    __shared__ float vecs[4][HIDC];
    int tid = threadIdx.x;
    for (int i = tid; i < HIDC * HIDC; i += 256) {
        int j = i >> 6, k = i & 63;
        WT[k * 65 + j] = W[i];
    }
    __syncthreads();
    int w = tid >> 6, lane = tid & 63;
    int g = lane >> 4, c = lane & 15;
    float omb = 1.0f - beta;

    for (int n0 = blockIdx.x * 4; n0 < NN; n0 += gridDim.x * 4) {
        int n = n0 + w;
        bool valid = n < NN;                  // uniform per wave
        if (valid) {
            int e0 = offsets[n], e1 = offsets[n + 1];
            float4 acc = gather_node(h_in, adj, e0, e1, g, c);
            if (g == 0) {
                const float4 x0v = *reinterpret_cast<const float4*>(x0 + ((n << 6) + (c << 2)));
                float4 aggv;
                aggv.x = fmaf(0.9f, acc.x, 0.1f * x0v.x);
                aggv.y = fmaf(0.9f, acc.y, 0.1f * x0v.y);
                aggv.z = fmaf(0.9f, acc.z, 0.1f * x0v.z);
                aggv.w = fmaf(0.9f, acc.w, 0.1f * x0v.w);
                *reinterpret_cast<float4*>(&vecs[w][c << 2]) = aggv;
            }
        }
        __syncthreads();
        if (valid) {
            float vagg = vecs[w][lane];
            float dot = 0.0f;
            #pragma unroll 8
            for (int k = 0; k < HIDC; ++k)
                dot = fmaf(vecs[w][k], WT[k * 65 + lane], dot);
            float hn = fmaxf(fmaf(beta, dot, omb * vagg), 0.0f);
            h_out[(n << 6) + lane] = hn;
        }
        __syncthreads();
    }
}

// Stage 5b: final GCNII layer fused with the output linear.
__global__ __launch_bounds__(256) void layer_final(
        const float* __restrict__ h_in,
        const float* __restrict__ x0,
        const int* __restrict__ offsets, const int2* __restrict__ adj,
        const float* __restrict__ W, float beta,
        const float* __restrict__ w_out, const float* __restrict__ b_out,
        float* __restrict__ out) {
    __shared__ float WT[HIDC * 65];
    __shared__ float WoT[HIDC * 65];
    __shared__ float vecs[4][HIDC];
    int tid = threadIdx.x;
    for (int i = tid; i < HIDC * HIDC; i += 256) {
        int j = i >> 6, k = i & 63;
        WT[k * 65 + j]  = W[i];
        WoT[k * 65 + j] = w_out[i];
    }
    __syncthreads();
    int w = tid >> 6, lane = tid & 63;
    int g = lane >> 4, c = lane & 15;
    float omb = 1.0f - beta;
    float boj = b_out[lane];

    for (int n0 = blockIdx.x * 4; n0 < NN; n0 += gridDim.x * 4) {
        int n = n0 + w;
        bool valid = n < NN;
        if (valid) {
            int e0 = offsets[n], e1 = offsets[n + 1];
            float4 acc = gather_node(h_in, adj, e0, e1, g, c);
            if (g == 0) {
                const float4 x0v = *reinterpret_cast<const float4*>(x0 + ((n << 6) + (c << 2)));
                float4 aggv;
                aggv.x = fmaf(0.9f, acc.x, 0.1f * x0v.x);
                aggv.y = fmaf(0.9f, acc.y, 0.1f * x0v.y);
                aggv.z = fmaf(0.9f, acc.z, 0.1f * x0v.z);
                aggv.w = fmaf(0.9f, acc.w, 0.1f * x0v.w);
                *reinterpret_cast<float4*>(&vecs[w][c << 2]) = aggv;
            }
        }
        __syncthreads();
        float hn = 0.0f;
        if (valid) {
            float vagg = vecs[w][lane];
            float dot = 0.0f;
            #pragma unroll 8
            for (int k = 0; k < HIDC; ++k)
                dot = fmaf(vecs[w][k], WT[k * 65 + lane], dot);
            hn = fmaxf(fmaf(beta, dot, omb * vagg), 0.0f);
        }
        __syncthreads();
        vecs[w][lane] = hn;
        __syncthreads();
        if (valid) {
            float acc2 = boj;
            #pragma unroll 8
            for (int k = 0; k < HIDC; ++k)
                acc2 = fmaf(vecs[w][k], WoT[k * 65 + lane], acc2);
            out[(n << 6) + lane] = acc2;
        }
        __syncthreads();
    }
}

extern "C" void kernel_launch(void* const* d_in, const int* in_sizes, int n_in,
                              void* d_out, int out_size, void* d_ws, size_t ws_size,
                              hipStream_t stream) {
    const float* x      = (const float*)d_in[0];
    const void*  ei     = d_in[1];
    const float* w_in   = (const float*)d_in[2];
    const float* b_in   = (const float*)d_in[3];
    const float* conv_w = (const float*)d_in[4];
    const float* w_out  = (const float*)d_in[5];
    const float* b_out  = (const float*)d_in[6];
    float* out = (float*)d_out;

    char* ws = (char*)d_ws;
    size_t off = 0;
    auto alloc = [&](size_t bytes) -> void* {
        void* p = ws + off;
        off += (bytes + 255) & ~(size_t)255;
        return p;
    };
    int*   flag    = (int*)alloc(4);
    int*   degi    = (int*)alloc((size_t)NN * 4);
    float* dinv    = (float*)alloc((size_t)NN * 4);
    int*   offsets = (int*)alloc((size_t)(NN + 1) * 4);
    int*   cursor  = (int*)alloc((size_t)NN * 4);
    int2*  adj     = (int2*)alloc((size_t)TOT * 8);
    float* hA      = (float*)alloc((size_t)NN * HIDC * 4);
    float* hB      = (float*)alloc((size_t)NN * HIDC * 4);
    float* x0      = (float*)alloc((size_t)NN * HIDC * 4);

    hipMemsetAsync(flag, 0, 4, stream);
    hipMemsetAsync(degi, 0, (size_t)NN * 4, stream);
    detect_kernel<<<256, 256, 0, stream>>>((const long long*)ei, flag);
    deg_kernel<<<(TOT + 255) / 256, 256, 0, stream>>>(ei, flag, degi);
    dinv_kernel<<<(NN + 255) / 256, 256, 0, stream>>>(degi, dinv);
    scan_kernel<<<1, 1024, 0, stream>>>(degi, offsets);
    hipMemcpyAsync(cursor, offsets, (size_t)NN * 4, hipMemcpyDeviceToDevice, stream);
    fill_kernel<<<(TOT + 255) / 256, 256, 0, stream>>>(ei, flag, dinv, cursor, adj);
    in_gemm<<<1024, 256, 0, stream>>>(x, w_in, b_in, hA, x0);

    float* cur = hA;
    float* nxt = hB;
    for (int l = 0; l < LLAYERS; ++l) {
        float beta = logf(0.5f / (float)(l + 1) + 1.0f);
        const float* Wl = conv_w + (size_t)l * HIDC * HIDC;
        if (l < LLAYERS - 1) {
            layer_mid<<<2048, 256, 0, stream>>>(cur, nxt, x0, offsets, adj, Wl, beta);
            float* t = cur; cur = nxt; nxt = t;
        } else {
            layer_final<<<2048, 256, 0, stream>>>(cur, x0, offsets, adj, Wl, beta,
                                                  w_out, b_out, out);
        }
    }
}

// Round 6
// 497.987 us; speedup vs baseline: 1.3049x; 1.1333x over previous
//
#include <hip/hip_runtime.h>
#include <math.h>

#define NN 50000
#define EE 800000
#define INC 128
#define HIDC 64
#define OUTC 64
#define LLAYERS 8
#define TOT (EE + NN)
#define SCAN_B 200   // ceil(NN/256)

// ---------------------------------------------------------------------------
// Stage 0: detect whether edge_index was delivered as int64 or int32.
__global__ void detect_kernel(const long long* __restrict__ p, int* __restrict__ flag) {
    int stride = gridDim.x * blockDim.x;
    int bad = 0;
    for (int i = blockIdx.x * blockDim.x + threadIdx.x; i < EE; i += stride) {
        long long v = p[i];
        bad |= (v < 0 || v >= NN);
    }
    if (bad) atomicOr(flag, 1);   // flag=1 -> int32 layout
}

__device__ __forceinline__ int load_row(const void* ei, int is64, int e) {
    return is64 ? (int)((const long long*)ei)[e] : ((const int*)ei)[e];
}
__device__ __forceinline__ int load_col(const void* ei, int is64, int e) {
    return is64 ? (int)((const long long*)ei)[EE + e] : ((const int*)ei)[EE + e];
}

// Stage 1: in-degree of col (self-loops included)
__global__ void deg_kernel(const void* __restrict__ ei, const int* __restrict__ flag,
                           int* __restrict__ degi) {
    int i = blockIdx.x * blockDim.x + threadIdx.x;
    if (i >= TOT) return;
    int is64 = (*flag == 0);
    int c = (i < EE) ? load_col(ei, is64, i) : (i - EE);
    atomicAdd(&degi[c], 1);
}

__global__ void dinv_kernel(const int* __restrict__ degi, float* __restrict__ dinv) {
    int i = blockIdx.x * blockDim.x + threadIdx.x;
    if (i < NN) {
        int d = degi[i];
        dinv[i] = d > 0 ? 1.0f / sqrtf((float)d) : 0.0f;
    }
}

// ---------------------------------------------------------------------------
// Stage 2: 3-kernel device-wide exclusive scan (replaces the 76.5us
// single-block scan that was the largest dispatch in the whole call).
// A: per-block (256-elem slice) reduction -> bsum[200]
__global__ __launch_bounds__(256) void scan_part(const int* __restrict__ degi,
                                                 int* __restrict__ bsum) {
    __shared__ int s[256];
    int t = threadIdx.x;
    int i = blockIdx.x * 256 + t;
    s[t] = (i < NN) ? degi[i] : 0;
    __syncthreads();
    for (int off = 128; off > 0; off >>= 1) {
        if (t < off) s[t] += s[t + off];
        __syncthreads();
    }
    if (t == 0) bsum[blockIdx.x] = s[0];
}

// B: exclusive scan of the 200 block sums (single tiny block)
__global__ __launch_bounds__(256) void scan_bsum(int* __restrict__ bsum) {
    __shared__ int s[256];
    int t = threadIdx.x;
    int v = (t < SCAN_B) ? bsum[t] : 0;
    s[t] = v;
    __syncthreads();
    for (int off = 1; off < 256; off <<= 1) {
        int add = (t >= off) ? s[t - off] : 0;
        __syncthreads();
        s[t] += add;
        __syncthreads();
    }
    if (t < SCAN_B) bsum[t] = s[t] - v;   // exclusive
}

// C: block-local exclusive scan + scanned blocksum -> offsets[]
__global__ __launch_bounds__(256) void scan_final(const int* __restrict__ degi,
                                                  const int* __restrict__ bsum,
                                                  int* __restrict__ offsets) {
    __shared__ int s[256];
    int t = threadIdx.x;
    int i = blockIdx.x * 256 + t;
    int v = (i < NN) ? degi[i] : 0;
    s[t] = v;
    __syncthreads();
    for (int off = 1; off < 256; off <<= 1) {
        int add = (t >= off) ? s[t - off] : 0;
        __syncthreads();
        s[t] += add;
        __syncthreads();
    }
    if (i < NN) {
        int off_i = bsum[blockIdx.x] + s[t] - v;   // exclusive prefix of degi[i]
        offsets[i] = off_i;
        if (i == NN - 1) offsets[NN] = off_i + v;
    }
}

// Stage 3: fill CSR adjacency (src, norm) sorted by destination
__global__ void fill_kernel(const void* __restrict__ ei, const int* __restrict__ flag,
                            const float* __restrict__ dinv, int* __restrict__ cursor,
                            int2* __restrict__ adj) {
    int i = blockIdx.x * blockDim.x + threadIdx.x;
    if (i >= TOT) return;
    int is64 = (*flag == 0);
    int r, c;
    if (i < EE) { r = load_row(ei, is64, i); c = load_col(ei, is64, i); }
    else        { r = i - EE; c = r; }
    int pos = atomicAdd(&cursor[c], 1);
    adj[pos] = make_int2(r, __float_as_int(dinv[r] * dinv[c]));
}

// Stage 4: h = relu(x @ w_in^T + b_in); also x0 = h.
__global__ __launch_bounds__(256) void in_gemm(const float* __restrict__ x,
                                               const float* __restrict__ w_in,
                                               const float* __restrict__ b_in,
                                               float* __restrict__ h,
                                               float* __restrict__ x0) {
    __shared__ float wT[INC * 65];
    __shared__ float xs[4][INC];
    int tid = threadIdx.x;
    for (int i = tid; i < HIDC * INC; i += 256) {
        int j = i >> 7, k = i & 127;          // w_in[j][k], row-major [64][128]
        wT[k * 65 + j] = w_in[i];
    }
    __syncthreads();
    int w = tid >> 6, lane = tid & 63;
    float bj = b_in[lane];
    for (int n0 = blockIdx.x * 4; n0 < NN; n0 += gridDim.x * 4) {
        int n = n0 + w;
        bool valid = n < NN;
        if (valid) {
            xs[w][lane]      = x[(size_t)n * INC + lane];
            xs[w][lane + 64] = x[(size_t)n * INC + 64 + lane];
        }
        __syncthreads();
        if (valid) {
            float acc = bj;
            #pragma unroll 8
            for (int k = 0; k < INC; ++k)
                acc = fmaf(xs[w][k], wT[k * 65 + lane], acc);
            float v = fmaxf(acc, 0.0f);
            h[(size_t)n * HIDC + lane]  = v;
            x0[(size_t)n * HIDC + lane] = v;
        }
        __syncthreads();
    }
}

// ---------------------------------------------------------------------------
// Gather core: wave handles node n. lane = g*16 + c (g = edge-group 0..3,
// c = channel-quad 0..15). Group g walks edges e0+g, e0+g+4, ... Each
// vector-load instruction fetches FOUR distinct h rows (4 groups x 16 lanes
// x float4 = 4 x 256B), quadrupling cache lines in flight vs lane=channel.
__device__ __forceinline__ float4 gather_node(const float* __restrict__ h_in,
                                              const int2* __restrict__ adj,
                                              int e0, int e1, int g, int c) {
    float4 acc = make_float4(0.f, 0.f, 0.f, 0.f);
    #pragma unroll 2
    for (int e = e0 + g; e < e1; e += 4) {
        int2 a = adj[e];
        const float4 hv = *reinterpret_cast<const float4*>(h_in + ((a.x << 6) + (c << 2)));
        float nrm = __int_as_float(a.y);
        acc.x = fmaf(nrm, hv.x, acc.x);
        acc.y = fmaf(nrm, hv.y, acc.y);
        acc.z = fmaf(nrm, hv.z, acc.z);
        acc.w = fmaf(nrm, hv.w, acc.w);
    }
    // reduce across the 4 groups (lanes differing in bits 4..5)
    acc.x += __shfl_xor(acc.x, 16); acc.y += __shfl_xor(acc.y, 16);
    acc.z += __shfl_xor(acc.z, 16); acc.w += __shfl_xor(acc.w, 16);
    acc.x += __shfl_xor(acc.x, 32); acc.y += __shfl_xor(acc.y, 32);
    acc.z += __shfl_xor(acc.z, 32); acc.w += __shfl_xor(acc.w, 32);
    return acc;
}

// Stage 5a: middle GCNII layer (17.7KB LDS -> 8 blocks/CU)
__global__ __launch_bounds__(256) void layer_mid(
        const float* __restrict__ h_in, float* __restrict__ h_out,
        const float* __restrict__ x0,
        const int* __restrict__ offsets, const int2* __restrict__ adj,
        const float* __restrict__ W, float beta) {
    __shared__ float WT[HIDC * 65];
    __shared__ float vecs[4][HIDC];
    int tid = threadIdx.x;
    for (int i = tid; i < HIDC * HIDC; i += 256) {
        int j = i >> 6, k = i & 63;
        WT[k * 65 + j] = W[i];
    }
    __syncthreads();
    int w = tid >> 6, lane = tid & 63;
    int g = lane >> 4, c = lane & 15;
    float omb = 1.0f - beta;

    for (int n0 = blockIdx.x * 4; n0 < NN; n0 += gridDim.x * 4) {
        int n = n0 + w;
        bool valid = n < NN;                  // uniform per wave
        if (valid) {
            int e0 = offsets[n], e1 = offsets[n + 1];
            float4 acc = gather_node(h_in, adj, e0, e1, g, c);
            if (g == 0) {
                const float4 x0v = *reinterpret_cast<const float4*>(x0 + ((n << 6) + (c << 2)));
                float4 aggv;
                aggv.x = fmaf(0.9f, acc.x, 0.1f * x0v.x);
                aggv.y = fmaf(0.9f, acc.y, 0.1f * x0v.y);
                aggv.z = fmaf(0.9f, acc.z, 0.1f * x0v.z);
                aggv.w = fmaf(0.9f, acc.w, 0.1f * x0v.w);
                *reinterpret_cast<float4*>(&vecs[w][c << 2]) = aggv;
            }
        }
        __syncthreads();
        if (valid) {
            float vagg = vecs[w][lane];
            float dot = 0.0f;
            #pragma unroll 8
            for (int k = 0; k < HIDC; ++k)
                dot = fmaf(vecs[w][k], WT[k * 65 + lane], dot);
            float hn = fmaxf(fmaf(beta, dot, omb * vagg), 0.0f);
            h_out[(n << 6) + lane] = hn;
        }
        __syncthreads();
    }
}

// Stage 5b: final GCNII layer fused with the output linear.
__global__ __launch_bounds__(256) void layer_final(
        const float* __restrict__ h_in,
        const float* __restrict__ x0,
        const int* __restrict__ offsets, const int2* __restrict__ adj,
        const float* __restrict__ W, float beta,
        const float* __restrict__ w_out, const float* __restrict__ b_out,
        float* __restrict__ out) {
    __shared__ float WT[HIDC * 65];
    __shared__ float WoT[HIDC * 65];
    __shared__ float vecs[4][HIDC];
    int tid = threadIdx.x;
    for (int i = tid; i < HIDC * HIDC; i += 256) {
        int j = i >> 6, k = i & 63;
        WT[k * 65 + j]  = W[i];
        WoT[k * 65 + j] = w_out[i];
    }
    __syncthreads();
    int w = tid >> 6, lane = tid & 63;
    int g = lane >> 4, c = lane & 15;
    float omb = 1.0f - beta;
    float boj = b_out[lane];

    for (int n0 = blockIdx.x * 4; n0 < NN; n0 += gridDim.x * 4) {
        int n = n0 + w;
        bool valid = n < NN;
        if (valid) {
            int e0 = offsets[n], e1 = offsets[n + 1];
            float4 acc = gather_node(h_in, adj, e0, e1, g, c);
            if (g == 0) {
                const float4 x0v = *reinterpret_cast<const float4*>(x0 + ((n << 6) + (c << 2)));
                float4 aggv;
                aggv.x = fmaf(0.9f, acc.x, 0.1f * x0v.x);
                aggv.y = fmaf(0.9f, acc.y, 0.1f * x0v.y);
                aggv.z = fmaf(0.9f, acc.z, 0.1f * x0v.z);
                aggv.w = fmaf(0.9f, acc.w, 0.1f * x0v.w);
                *reinterpret_cast<float4*>(&vecs[w][c << 2]) = aggv;
            }
        }
        __syncthreads();
        float hn = 0.0f;
        if (valid) {
            float vagg = vecs[w][lane];
            float dot = 0.0f;
            #pragma unroll 8
            for (int k = 0; k < HIDC; ++k)
                dot = fmaf(vecs[w][k], WT[k * 65 + lane], dot);
            hn = fmaxf(fmaf(beta, dot, omb * vagg), 0.0f);
        }
        __syncthreads();
        vecs[w][lane] = hn;
        __syncthreads();
        if (valid) {
            float acc2 = boj;
            #pragma unroll 8
            for (int k = 0; k < HIDC; ++k)
                acc2 = fmaf(vecs[w][k], WoT[k * 65 + lane], acc2);
            out[(n << 6) + lane] = acc2;
        }
        __syncthreads();
    }
}

extern "C" void kernel_launch(void* const* d_in, const int* in_sizes, int n_in,
                              void* d_out, int out_size, void* d_ws, size_t ws_size,
                              hipStream_t stream) {
    const float* x      = (const float*)d_in[0];
    const void*  ei     = d_in[1];
    const float* w_in   = (const float*)d_in[2];
    const float* b_in   = (const float*)d_in[3];
    const float* conv_w = (const float*)d_in[4];
    const float* w_out  = (const float*)d_in[5];
    const float* b_out  = (const float*)d_in[6];
    float* out = (float*)d_out;

    char* ws = (char*)d_ws;
    size_t off = 0;
    auto alloc = [&](size_t bytes) -> void* {
        void* p = ws + off;
        off += (bytes + 255) & ~(size_t)255;
        return p;
    };
    int*   flag    = (int*)alloc(4);
    int*   degi    = (int*)alloc((size_t)NN * 4);
    float* dinv    = (float*)alloc((size_t)NN * 4);
    int*   offsets = (int*)alloc((size_t)(NN + 1) * 4);
    int*   cursor  = (int*)alloc((size_t)NN * 4);
    int*   bsum    = (int*)alloc((size_t)SCAN_B * 4);
    int2*  adj     = (int2*)alloc((size_t)TOT * 8);
    float* hA      = (float*)alloc((size_t)NN * HIDC * 4);
    float* hB      = (float*)alloc((size_t)NN * HIDC * 4);
    float* x0      = (float*)alloc((size_t)NN * HIDC * 4);

    hipMemsetAsync(flag, 0, 4, stream);
    hipMemsetAsync(degi, 0, (size_t)NN * 4, stream);
    detect_kernel<<<256, 256, 0, stream>>>((const long long*)ei, flag);
    deg_kernel<<<(TOT + 255) / 256, 256, 0, stream>>>(ei, flag, degi);
    dinv_kernel<<<(NN + 255) / 256, 256, 0, stream>>>(degi, dinv);
    scan_part<<<SCAN_B, 256, 0, stream>>>(degi, bsum);
    scan_bsum<<<1, 256, 0, stream>>>(bsum);
    scan_final<<<SCAN_B, 256, 0, stream>>>(degi, bsum, offsets);
    hipMemcpyAsync(cursor, offsets, (size_t)NN * 4, hipMemcpyDeviceToDevice, stream);
    fill_kernel<<<(TOT + 255) / 256, 256, 0, stream>>>(ei, flag, dinv, cursor, adj);
    in_gemm<<<1024, 256, 0, stream>>>(x, w_in, b_in, hA, x0);

    float* cur = hA;
    float* nxt = hB;
    for (int l = 0; l < LLAYERS; ++l) {
        float beta = logf(0.5f / (float)(l + 1) + 1.0f);
        const float* Wl = conv_w + (size_t)l * HIDC * HIDC;
        if (l < LLAYERS - 1) {
            layer_mid<<<2048, 256, 0, stream>>>(cur, nxt, x0, offsets, adj, Wl, beta);
            float* t = cur; cur = nxt; nxt = t;
        } else {
            layer_final<<<2048, 256, 0, stream>>>(cur, x0, offsets, adj, Wl, beta,
                                                  w_out, b_out, out);
        }
    }
}

// Round 8
// 471.435 us; speedup vs baseline: 1.3784x; 1.0563x over previous
//
#include <hip/hip_runtime.h>
#include <math.h>

#define NN 50000
#define EE 800000
#define INC 128
#define HIDC 64
#define OUTC 64
#define LLAYERS 8
#define TOT (EE + NN)
#define SCAN_B 200   // ceil(NN/256)

// Wave-internal LDS fence: orders this wave's ds_write -> ds_read without a
// block barrier (vecs[w] is private to wave w; no cross-wave sharing).
#define WAVE_LDS_FENCE() asm volatile("s_waitcnt lgkmcnt(0)" ::: "memory")

// ---------------------------------------------------------------------------
// Stage 0: detect whether edge_index was delivered as int64 or int32.
__global__ void detect_kernel(const long long* __restrict__ p, int* __restrict__ flag) {
    int stride = gridDim.x * blockDim.x;
    int bad = 0;
    for (int i = blockIdx.x * blockDim.x + threadIdx.x; i < EE; i += stride) {
        long long v = p[i];
        bad |= (v < 0 || v >= NN);
    }
    if (bad) atomicOr(flag, 1);   // flag=1 -> int32 layout
}

__device__ __forceinline__ int load_row(const void* ei, int is64, int e) {
    return is64 ? (int)((const long long*)ei)[e] : ((const int*)ei)[e];
}
__device__ __forceinline__ int load_col(const void* ei, int is64, int e) {
    return is64 ? (int)((const long long*)ei)[EE + e] : ((const int*)ei)[EE + e];
}

// Stage 1: in-degree of col (self-loops included)
__global__ void deg_kernel(const void* __restrict__ ei, const int* __restrict__ flag,
                           int* __restrict__ degi) {
    int i = blockIdx.x * blockDim.x + threadIdx.x;
    if (i >= TOT) return;
    int is64 = (*flag == 0);
    int c = (i < EE) ? load_col(ei, is64, i) : (i - EE);
    atomicAdd(&degi[c], 1);
}

__global__ void dinv_kernel(const int* __restrict__ degi, float* __restrict__ dinv) {
    int i = blockIdx.x * blockDim.x + threadIdx.x;
    if (i < NN) {
        int d = degi[i];
        dinv[i] = d > 0 ? 1.0f / sqrtf((float)d) : 0.0f;
    }
}

// ---------------------------------------------------------------------------
// Stage 2: 3-kernel device-wide exclusive scan
__global__ __launch_bounds__(256) void scan_part(const int* __restrict__ degi,
                                                 int* __restrict__ bsum) {
    __shared__ int s[256];
    int t = threadIdx.x;
    int i = blockIdx.x * 256 + t;
    s[t] = (i < NN) ? degi[i] : 0;
    __syncthreads();
    for (int off = 128; off > 0; off >>= 1) {
        if (t < off) s[t] += s[t + off];
        __syncthreads();
    }
    if (t == 0) bsum[blockIdx.x] = s[0];
}

__global__ __launch_bounds__(256) void scan_bsum(int* __restrict__ bsum) {
    __shared__ int s[256];
    int t = threadIdx.x;
    int v = (t < SCAN_B) ? bsum[t] : 0;
    s[t] = v;
    __syncthreads();
    for (int off = 1; off < 256; off <<= 1) {
        int add = (t >= off) ? s[t - off] : 0;
        __syncthreads();
        s[t] += add;
        __syncthreads();
    }
    if (t < SCAN_B) bsum[t] = s[t] - v;   // exclusive
}

__global__ __launch_bounds__(256) void scan_final(const int* __restrict__ degi,
                                                  const int* __restrict__ bsum,
                                                  int* __restrict__ offsets) {
    __shared__ int s[256];
    int t = threadIdx.x;
    int i = blockIdx.x * 256 + t;
    int v = (i < NN) ? degi[i] : 0;
    s[t] = v;
    __syncthreads();
    for (int off = 1; off < 256; off <<= 1) {
        int add = (t >= off) ? s[t - off] : 0;
        __syncthreads();
        s[t] += add;
        __syncthreads();
    }
    if (i < NN) {
        int off_i = bsum[blockIdx.x] + s[t] - v;   // exclusive prefix of degi[i]
        offsets[i] = off_i;
        if (i == NN - 1) offsets[NN] = off_i + v;
    }
}

// Stage 3: fill CSR adjacency (src, norm) sorted by destination
__global__ void fill_kernel(const void* __restrict__ ei, const int* __restrict__ flag,
                            const float* __restrict__ dinv, int* __restrict__ cursor,
                            int2* __restrict__ adj) {
    int i = blockIdx.x * blockDim.x + threadIdx.x;
    if (i >= TOT) return;
    int is64 = (*flag == 0);
    int r, c;
    if (i < EE) { r = load_row(ei, is64, i); c = load_col(ei, is64, i); }
    else        { r = i - EE; c = r; }
    int pos = atomicAdd(&cursor[c], 1);
    adj[pos] = make_int2(r, __float_as_int(dinv[r] * dinv[c]));
}

// Stage 4: h = relu(x @ w_in^T + b_in); also x0 = h.
// Per-wave x staging; no per-iteration block barrier (xs[w] is wave-private).
__global__ __launch_bounds__(256) void in_gemm(const float* __restrict__ x,
                                               const float* __restrict__ w_in,
                                               const float* __restrict__ b_in,
                                               float* __restrict__ h,
                                               float* __restrict__ x0) {
    __shared__ float wT[INC * 65];
    __shared__ float xs[4][INC];
    int tid = threadIdx.x;
    for (int i = tid; i < HIDC * INC; i += 256) {
        int j = i >> 7, k = i & 127;          // w_in[j][k], row-major [64][128]
        wT[k * 65 + j] = w_in[i];
    }
    __syncthreads();
    int w = tid >> 6, lane = tid & 63;
    float bj = b_in[lane];
    for (int n0 = blockIdx.x * 4; n0 < NN; n0 += gridDim.x * 4) {
        int n = n0 + w;
        if (n < NN) {
            xs[w][lane]      = x[(size_t)n * INC + lane];
            xs[w][lane + 64] = x[(size_t)n * INC + 64 + lane];
            WAVE_LDS_FENCE();
            float acc = bj;
            #pragma unroll 8
            for (int k = 0; k < INC; ++k)
                acc = fmaf(xs[w][k], wT[k * 65 + lane], acc);
            float v = fmaxf(acc, 0.0f);
            h[(size_t)n * HIDC + lane]  = v;
            x0[(size_t)n * HIDC + lane] = v;
        }
    }
}

// ---------------------------------------------------------------------------
// Gather core: wave handles node n. lane = g*16 + c (g = edge-group 0..3,
// c = channel-quad 0..15). Group g walks edges e0+g, e0+g+4, ... Each
// vector-load instruction fetches FOUR distinct h rows (4 groups x 16 lanes
// x float4 = 4 x 256B).
__device__ __forceinline__ float4 gather_node(const float* __restrict__ h_in,
                                              const int2* __restrict__ adj,
                                              int e0, int e1, int g, int c) {
    float4 acc = make_float4(0.f, 0.f, 0.f, 0.f);
    #pragma unroll 2
    for (int e = e0 + g; e < e1; e += 4) {
        int2 a = adj[e];
        const float4 hv = *reinterpret_cast<const float4*>(h_in + ((a.x << 6) + (c << 2)));
        float nrm = __int_as_float(a.y);
        acc.x = fmaf(nrm, hv.x, acc.x);
        acc.y = fmaf(nrm, hv.y, acc.y);
        acc.z = fmaf(nrm, hv.z, acc.z);
        acc.w = fmaf(nrm, hv.w, acc.w);
    }
    // reduce across the 4 groups (lanes differing in bits 4..5)
    acc.x += __shfl_xor(acc.x, 16); acc.y += __shfl_xor(acc.y, 16);
    acc.z += __shfl_xor(acc.z, 16); acc.w += __shfl_xor(acc.w, 16);
    acc.x += __shfl_xor(acc.x, 32); acc.y += __shfl_xor(acc.y, 32);
    acc.z += __shfl_xor(acc.z, 32); acc.w += __shfl_xor(acc.w, 32);
    return acc;
}

// Stage 5: GCNII layer, used for ALL 8 layers. No per-iteration block
// barriers: vecs[w] is wave-private, so waves run fully decoupled (degrees
// are Poisson(17) -- a block barrier would make 4 waves wait on the slowest
// gather every iteration).
__global__ __launch_bounds__(256, 8) void layer_mid(
        const float* __restrict__ h_in, float* __restrict__ h_out,
        const float* __restrict__ x0,
        const int* __restrict__ offsets, const int2* __restrict__ adj,
        const float* __restrict__ W, float beta) {
    __shared__ float WT[HIDC * 65];
    __shared__ float vecs[4][HIDC];
    int tid = threadIdx.x;
    for (int i = tid; i < HIDC * HIDC; i += 256) {
        int j = i >> 6, k = i & 63;
        WT[k * 65 + j] = W[i];
    }
    __syncthreads();
    int w = tid >> 6, lane = tid & 63;
    int g = lane >> 4, c = lane & 15;
    float omb = 1.0f - beta;

    for (int n0 = blockIdx.x * 4; n0 < NN; n0 += gridDim.x * 4) {
        int n = n0 + w;
        if (n < NN) {                          // uniform per wave
            int e0 = offsets[n], e1 = offsets[n + 1];
            float4 acc = gather_node(h_in, adj, e0, e1, g, c);
            if (g == 0) {
                const float4 x0v = *reinterpret_cast<const float4*>(x0 + ((n << 6) + (c << 2)));
                float4 aggv;
                aggv.x = fmaf(0.9f, acc.x, 0.1f * x0v.x);
                aggv.y = fmaf(0.9f, acc.y, 0.1f * x0v.y);
                aggv.z = fmaf(0.9f, acc.z, 0.1f * x0v.z);
                aggv.w = fmaf(0.9f, acc.w, 0.1f * x0v.w);
                *reinterpret_cast<float4*>(&vecs[w][c << 2]) = aggv;
            }
            WAVE_LDS_FENCE();
            float vagg = vecs[w][lane];
            float dot = 0.0f;
            #pragma unroll 8
            for (int k = 0; k < HIDC; ++k)
                dot = fmaf(vecs[w][k], WT[k * 65 + lane], dot);
            float hn = fmaxf(fmaf(beta, dot, omb * vagg), 0.0f);
            h_out[(n << 6) + lane] = hn;
        }
    }
}

// Stage 6: out = h @ w_out^T + b_out (split from the last layer so the layer
// kernel keeps 17.7KB LDS / 8 blocks/CU instead of 34KB / 4).
__global__ __launch_bounds__(256, 8) void out_gemm(const float* __restrict__ h,
                                                   const float* __restrict__ w_out,
                                                   const float* __restrict__ b_out,
                                                   float* __restrict__ out) {
    __shared__ float WoT[HIDC * 65];
    __shared__ float vecs[4][HIDC];
    int tid = threadIdx.x;
    for (int i = tid; i < HIDC * HIDC; i += 256) {
        int j = i >> 6, k = i & 63;
        WoT[k * 65 + j] = w_out[i];
    }
    __syncthreads();
    int w = tid >> 6, lane = tid & 63;
    float bj = b_out[lane];
    for (int n0 = blockIdx.x * 4; n0 < NN; n0 += gridDim.x * 4) {
        int n = n0 + w;
        if (n < NN) {
            vecs[w][lane] = h[(n << 6) + lane];
            WAVE_LDS_FENCE();
            float acc = bj;
            #pragma unroll 8
            for (int k = 0; k < HIDC; ++k)
                acc = fmaf(vecs[w][k], WoT[k * 65 + lane], acc);
            out[(n << 6) + lane] = acc;
        }
    }
}

extern "C" void kernel_launch(void* const* d_in, const int* in_sizes, int n_in,
                              void* d_out, int out_size, void* d_ws, size_t ws_size,
                              hipStream_t stream) {
    const float* x      = (const float*)d_in[0];
    const void*  ei     = d_in[1];
    const float* w_in   = (const float*)d_in[2];
    const float* b_in   = (const float*)d_in[3];
    const float* conv_w = (const float*)d_in[4];
    const float* w_out  = (const float*)d_in[5];
    const float* b_out  = (const float*)d_in[6];
    float* out = (float*)d_out;

    char* ws = (char*)d_ws;
    size_t off = 0;
    auto alloc = [&](size_t bytes) -> void* {
        void* p = ws + off;
        off += (bytes + 255) & ~(size_t)255;
        return p;
    };
    int*   flag    = (int*)alloc(4);
    int*   degi    = (int*)alloc((size_t)NN * 4);
    float* dinv    = (float*)alloc((size_t)NN * 4);
    int*   offsets = (int*)alloc((size_t)(NN + 1) * 4);
    int*   cursor  = (int*)alloc((size_t)NN * 4);
    int*   bsum    = (int*)alloc((size_t)SCAN_B * 4);
    int2*  adj     = (int2*)alloc((size_t)TOT * 8);
    float* hA      = (float*)alloc((size_t)NN * HIDC * 4);
    float* hB      = (float*)alloc((size_t)NN * HIDC * 4);
    float* x0      = (float*)alloc((size_t)NN * HIDC * 4);

    hipMemsetAsync(flag, 0, 4, stream);
    hipMemsetAsync(degi, 0, (size_t)NN * 4, stream);
    detect_kernel<<<256, 256, 0, stream>>>((const long long*)ei, flag);
    deg_kernel<<<(TOT + 255) / 256, 256, 0, stream>>>(ei, flag, degi);
    dinv_kernel<<<(NN + 255) / 256, 256, 0, stream>>>(degi, dinv);
    scan_part<<<SCAN_B, 256, 0, stream>>>(degi, bsum);
    scan_bsum<<<1, 256, 0, stream>>>(bsum);
    scan_final<<<SCAN_B, 256, 0, stream>>>(degi, bsum, offsets);
    hipMemcpyAsync(cursor, offsets, (size_t)NN * 4, hipMemcpyDeviceToDevice, stream);
    fill_kernel<<<(TOT + 255) / 256, 256, 0, stream>>>(ei, flag, dinv, cursor, adj);
    in_gemm<<<1024, 256, 0, stream>>>(x, w_in, b_in, hA, x0);

    float* cur = hA;
    float* nxt = hB;
    for (int l = 0; l < LLAYERS; ++l) {
        float beta = logf(0.5f / (float)(l + 1) + 1.0f);
        const float* Wl = conv_w + (size_t)l * HIDC * HIDC;
        layer_mid<<<2048, 256, 0, stream>>>(cur, nxt, x0, offsets, adj, Wl, beta);
        float* t = cur; cur = nxt; nxt = t;
    }
    out_gemm<<<1024, 256, 0, stream>>>(cur, w_out, b_out, out);
}